// Round 3
// baseline (9527.787 us; speedup 1.0000x reference)
//
#include <hip/hip_runtime.h>
#include <hip/hip_bf16.h>

#define NN 4096
#define LN2F 0.6931471805599453f

__device__ inline float block_reduce(float v, float* sdata){
  int tid = threadIdx.x;
  sdata[tid] = v; __syncthreads();
  for(int s=128; s>0; s>>=1){
    if(tid < s) sdata[tid] += sdata[tid+s];
    __syncthreads();
  }
  float r = sdata[0];
  __syncthreads();
  return r;
}

// ---------------------------------------------------------------------------
// adjacency: mult[i][j] = (dot(df_i,df_j) > 0) + (i==j), 2-bit packed:
// mult2[row*1024 + (col>>2)], bits (col&3)*2. Bitwise-symmetric.
// ---------------------------------------------------------------------------
__global__ __launch_bounds__(256)
void adj_k(const float* __restrict__ A, unsigned char* __restrict__ mult2)
{
  __shared__ float As[16][65], Bs[16][65];
  const int tid = threadIdx.x;
  const int bm = blockIdx.y*64, bn = blockIdx.x*64;
  const int tx = tid & 15, ty = tid >> 4;
  const int r  = tid >> 2, kq = (tid & 3) * 4;
  float acc[4][4] = {};
  for(int kb=0; kb<2048; kb+=16){
    #pragma unroll
    for(int q=0;q<4;q++){
      As[kq+q][r] = A[(size_t)(bm+r)*2048 + kb+kq+q];
      Bs[kq+q][r] = A[(size_t)(bn+r)*2048 + kb+kq+q];
    }
    __syncthreads();
    #pragma unroll
    for(int k=0;k<16;k++){
      float a[4], b[4];
      #pragma unroll
      for(int i=0;i<4;i++) a[i]=As[k][ty*4+i];
      #pragma unroll
      for(int j=0;j<4;j++) b[j]=Bs[k][tx*4+j];
      #pragma unroll
      for(int i=0;i<4;i++)
        #pragma unroll
        for(int j=0;j<4;j++) acc[i][j] += a[i]*b[j];
    }
    __syncthreads();
  }
  #pragma unroll
  for(int i=0;i<4;i++){
    int row = bm + ty*4 + i;
    unsigned char byte = 0;
    #pragma unroll
    for(int j=0;j<4;j++){
      int col = bn + tx*4 + j;
      int mu = (acc[i][j] > 0.f ? 1 : 0) + (row == col ? 1 : 0);
      byte |= (unsigned char)(mu << (2*j));
    }
    mult2[(size_t)row*1024 + (bn>>2) + tx] = byte;
  }
}

// ---------------------------------------------------------------------------
// tiled GEMM: C[M,Nn] = A@B (+C if ACC). EPI: 0 none, 2 bias+leaky0.01
// ---------------------------------------------------------------------------
template<int EPI, bool ACC>
__global__ __launch_bounds__(256)
void gemm_k(const float* __restrict__ A, const float* __restrict__ B,
            float* __restrict__ C, const float* __restrict__ bias,
            int M, int Nn, int K, int lda, int ldb, int ldc)
{
  __shared__ float As[16][65], Bs[16][65];
  const int tid = threadIdx.x;
  const int bm = blockIdx.y*64, bn = blockIdx.x*64;
  const int tx = tid & 15, ty = tid >> 4;
  const int ar = tid >> 2, ak = (tid & 3) * 4;
  const int bk = tid >> 4, bc = (tid & 15) * 4;
  float acc[4][4] = {};
  for(int kb=0; kb<K; kb+=16){
    #pragma unroll
    for(int q=0;q<4;q++)
      As[ak+q][ar] = A[(size_t)(bm+ar)*lda + kb+ak+q];
    #pragma unroll
    for(int q=0;q<4;q++)
      Bs[bk][bc+q] = B[(size_t)(kb+bk)*ldb + bn+bc+q];
    __syncthreads();
    #pragma unroll
    for(int k=0;k<16;k++){
      float a[4], b[4];
      #pragma unroll
      for(int i=0;i<4;i++) a[i]=As[k][ty*4+i];
      #pragma unroll
      for(int j=0;j<4;j++) b[j]=Bs[k][tx*4+j];
      #pragma unroll
      for(int i=0;i<4;i++)
        #pragma unroll
        for(int j=0;j<4;j++) acc[i][j] += a[i]*b[j];
    }
    __syncthreads();
  }
  #pragma unroll
  for(int i=0;i<4;i++){
    int r = bm + ty*4 + i;
    #pragma unroll
    for(int j=0;j<4;j++){
      int c = bn + tx*4 + j;
      float v = acc[i][j];
      if(ACC) v += C[(size_t)r*ldc + c];
      if(EPI==2){ v += bias[c]; v = v > 0.f ? v : 0.01f*v; }
      C[(size_t)r*ldc + c] = v;
    }
  }
}

// ---------------------------------------------------------------------------
// el/er: el[h*NN+n] = sum_d feat[n, h*D+d] * al[h*D+d]
// ---------------------------------------------------------------------------
__global__ __launch_bounds__(256)
void elr_k(const float* __restrict__ feat, const float* __restrict__ al,
           const float* __restrict__ ar, float* __restrict__ el,
           float* __restrict__ er, int H, int D)
{
  __shared__ float sdata[256];
  int n = blockIdx.x, tid = threadIdx.x;
  float accl[2] = {0.f, 0.f}, accr[2] = {0.f, 0.f};
  int HD = H * D;
  for(int k=tid; k<HD; k+=256){
    float f = feat[(size_t)n*HD + k];
    int h = k / D;
    accl[h] += f * al[k];
    accr[h] += f * ar[k];
  }
  for(int h=0; h<H; h++){
    float rl = block_reduce(accl[h], sdata);
    float rr = block_reduce(accr[h], sdata);
    if(tid==0){ el[h*NN + n] = rl; er[h*NN + n] = rr; }
  }
}

// ---------------------------------------------------------------------------
// column softmax stats per dst d over src s: t = leaky(el[s]+er[d],0.2),
// weight mu in {0,1,2}: m = max(t + ln mu), inv = 1/sum(mu*exp(t-m))
// ---------------------------------------------------------------------------
__global__ __launch_bounds__(256)
void colstats_k(const float* __restrict__ el, const float* __restrict__ er,
                const unsigned char* __restrict__ mult2,
                float* __restrict__ cm, float* __restrict__ cinv)
{
  int d = blockIdx.x*256 + threadIdx.x;
  const float erd = er[d];
  const int dbyte = d >> 2, dsh = (d & 3) * 2;
  float m = -1e30f;
  for(int s=0; s<NN; s++){
    int mu = (mult2[(size_t)s*1024 + dbyte] >> dsh) & 3;
    if(mu){
      float t = el[s] + erd;
      t = t > 0.f ? t : 0.2f*t;
      if(mu == 2) t += LN2F;
      m = fmaxf(m, t);
    }
  }
  float sum = 0.f;
  for(int s=0; s<NN; s++){
    int mu = (mult2[(size_t)s*1024 + dbyte] >> dsh) & 3;
    if(mu){
      float t = el[s] + erd;
      t = t > 0.f ? t : 0.2f*t;
      sum += (float)mu * __expf(t - m);
    }
  }
  cm[d] = m; cinv[d] = 1.f / sum;
}

// ---------------------------------------------------------------------------
// aggregation GEMM, alpha computed on the fly in the A-stage:
// C[d][c] = sum_s alpha[d][s]*B[s][c],
// alpha[d][s] = mu * exp(leaky(el[s]+er[d]) - m[d]) * inv[d].  EPI 1 = relu.
// ---------------------------------------------------------------------------
template<int EPI, bool ACC>
__global__ __launch_bounds__(256)
void agg_k(const unsigned char* __restrict__ mult2,
           const float* __restrict__ el, const float* __restrict__ er,
           const float* __restrict__ cm, const float* __restrict__ cinv,
           const float* __restrict__ B, float* __restrict__ C,
           int ldb, int ldc)
{
  __shared__ float As[16][65], Bs[16][65];
  const int tid = threadIdx.x;
  const int bm = blockIdx.y*64, bn = blockIdx.x*64;
  const int tx = tid & 15, ty = tid >> 4;
  const int ar = tid >> 2, ak = (tid & 3) * 4;
  const int bk = tid >> 4, bc = (tid & 15) * 4;
  const int d = bm + ar;
  const float erd = er[d], md = cm[d], invd = cinv[d];
  const size_t arow = (size_t)d * 1024;
  float acc[4][4] = {};
  for(int kb=0; kb<NN; kb+=16){
    unsigned char byte = mult2[arow + (kb>>2) + (tid&3)];
    #pragma unroll
    for(int q=0;q<4;q++){
      int s = kb + ak + q;
      int mu = (byte >> (2*q)) & 3;
      float t = el[s] + erd;
      t = t > 0.f ? t : 0.2f*t;
      As[ak+q][ar] = (float)mu * __expf(t - md) * invd;
    }
    #pragma unroll
    for(int q=0;q<4;q++)
      Bs[bk][bc+q] = B[(size_t)(kb+bk)*ldb + bn+bc+q];
    __syncthreads();
    #pragma unroll
    for(int k=0;k<16;k++){
      float a[4], b[4];
      #pragma unroll
      for(int i=0;i<4;i++) a[i]=As[k][ty*4+i];
      #pragma unroll
      for(int j=0;j<4;j++) b[j]=Bs[k][tx*4+j];
      #pragma unroll
      for(int i=0;i<4;i++)
        #pragma unroll
        for(int j=0;j<4;j++) acc[i][j] += a[i]*b[j];
    }
    __syncthreads();
  }
  #pragma unroll
  for(int i=0;i<4;i++){
    int r = bm + ty*4 + i;
    #pragma unroll
    for(int j=0;j<4;j++){
      int c = bn + tx*4 + j;
      float v = acc[i][j];
      if(ACC) v += C[(size_t)r*ldc + c];
      if(EPI==1) v = fmaxf(v, 0.f);
      C[(size_t)r*ldc + c] = v;
    }
  }
}

// ---------------------------------------------------------------------------
// skinny classifier: out[n][c] = X[n,:]·W[:,c] + b[c], C=10, f32 out
// ---------------------------------------------------------------------------
__global__ __launch_bounds__(256)
void cls_k(const float* __restrict__ X, const float* __restrict__ Wt,
           const float* __restrict__ b, float* __restrict__ out, int K)
{
  __shared__ float sdata[256];
  int n = blockIdx.x, tid = threadIdx.x;
  float acc[10] = {};
  for(int k=tid; k<K; k+=256){
    float xv = X[(size_t)n*K + k];
    #pragma unroll
    for(int c=0;c<10;c++) acc[c] += xv * Wt[k*10 + c];
  }
  for(int c=0;c<10;c++){
    float r = block_reduce(acc[c], sdata);
    if(tid==0) out[n*10 + c] = r + b[c];
  }
}

// ---------------------------------------------------------------------------
extern "C" void kernel_launch(void* const* d_in, const int* in_sizes, int n_in,
                              void* d_out, int out_size, void* d_ws, size_t ws_size,
                              hipStream_t stream) {
  (void)in_sizes; (void)n_in; (void)out_size; (void)ws_size;
  const float* df  = (const float*)d_in[0];
  const float* W1  = (const float*)d_in[1];
  const float* al1 = (const float*)d_in[2];
  const float* ar1 = (const float*)d_in[3];
  const float* W2  = (const float*)d_in[4];
  const float* al2 = (const float*)d_in[5];
  const float* ar2 = (const float*)d_in[6];
  const float* lw  = (const float*)d_in[7];
  const float* lb  = (const float*)d_in[8];
  const float* c1w = (const float*)d_in[9];
  const float* c1b = (const float*)d_in[10];
  const float* c2w = (const float*)d_in[11];
  const float* c2b = (const float*)d_in[12];
  float* out = (float*)d_out;

  char* Wp = (char*)d_ws;                              // high water ~44.2 MB
  unsigned char* mult2 = (unsigned char*)(Wp);         //  4 MB packed adjacency
  float* feat = (float*)(Wp + ( 4u<<20));              // 16 MB [4096,1024]
  float* x1   = (float*)(Wp + (20u<<20));              // 16 MB [4096,1024]
  float* x3   = x1;                                    // reuse (x1 dead by step 7)
  float* x2   = (float*)(Wp + (36u<<20));              //  8 MB [4096,512]
  float* S    = (float*)(Wp + (44u<<20));              // smalls ~176 KB
  float *el1=S,          *er1=S+4096;
  float *el2=S+8192,     *er2=S+16384;                 // [2*NN] each
  float *m1 =S+24576,    *i1 =S+28672;
  float *m2 =S+32768,    *i2 =S+40960;                 // [2*NN] each

  // 1) packed adjacency from sign of df @ df^T (f32, near-exact signs)
  adj_k<<<dim3(64,64),256,0,stream>>>(df, mult2);

  // 2) feat1 = df @ W1  [4096,1024]
  gemm_k<0,false><<<dim3(16,64),256,0,stream>>>(
      df, W1, feat, nullptr, NN, 1024, 2048, 2048, 1024, 1024);

  // 3) layer-1 scores + softmax stats
  elr_k<<<NN,256,0,stream>>>(feat, al1, ar1, el1, er1, 1, 1024);
  colstats_k<<<16,256,0,stream>>>(el1, er1, mult2, m1, i1);

  // 4) x1 = relu(alpha1 @ feat1)
  agg_k<1,false><<<dim3(16,64),256,0,stream>>>(
      mult2, el1, er1, m1, i1, feat, x1, 1024, 1024);

  // 5) feat2 = x1 @ W2  [4096,1024]
  gemm_k<0,false><<<dim3(16,64),256,0,stream>>>(
      x1, W2, feat, nullptr, NN, 1024, 1024, 1024, 1024, 1024);

  // 6) layer-2 scores (H=2,D=512), per-head softmax + aggregation, head-sum
  elr_k<<<NN,256,0,stream>>>(feat, al2, ar2, el2, er2, 2, 512);
  colstats_k<<<16,256,0,stream>>>(el2,    er2,    mult2, m2,    i2);
  colstats_k<<<16,256,0,stream>>>(el2+NN, er2+NN, mult2, m2+NN, i2+NN);
  agg_k<0,false><<<dim3(8,64),256,0,stream>>>(
      mult2, el2,    er2,    m2,    i2,    feat,       x2, 1024, 512);
  agg_k<0,true ><<<dim3(8,64),256,0,stream>>>(
      mult2, el2+NN, er2+NN, m2+NN, i2+NN, feat + 512, x2, 1024, 512);

  // 7) x3 = leaky([df, x2] @ lin1_w + b, 0.01), split over K (x3 reuses x1)
  gemm_k<0,false><<<dim3(16,64),256,0,stream>>>(
      df, lw, x3, nullptr, NN, 1024, 2048, 2048, 1024, 1024);
  gemm_k<2,true><<<dim3(16,64),256,0,stream>>>(
      x2, lw + (size_t)2048*1024, x3, lb, NN, 1024, 512, 512, 1024, 1024);

  // 8) classifiers -> f32 out (logits1 then logits2)
  cls_k<<<NN,256,0,stream>>>(x3, c1w, c1b, out, 1024);
  cls_k<<<NN,256,0,stream>>>(df, c2w, c2b, out + NN*10, 2048);
}

// Round 4
// 966.993 us; speedup vs baseline: 9.8530x; 9.8530x over previous
//
#include <hip/hip_runtime.h>
#include <hip/hip_bf16.h>

typedef __hip_bfloat16 bf16;
typedef __attribute__((ext_vector_type(8))) short short8;
typedef __attribute__((ext_vector_type(4))) float f32x4;

#define NN 4096
#define LN2F 0.69314718f

__device__ inline float br_sum(float v, float* sd){
  int t = threadIdx.x;
  sd[t] = v; __syncthreads();
  for(int s=128; s>0; s>>=1){ if(t<s) sd[t]+=sd[t+s]; __syncthreads(); }
  float r = sd[0]; __syncthreads();
  return r;
}

// flat f32 -> bf16 convert (4/thread)
__global__ __launch_bounds__(256)
void cvt_k(const float* __restrict__ src, bf16* __restrict__ dst, int n)
{
  int i = (blockIdx.x*256 + threadIdx.x)*4;
  if(i >= n) return;
  f32x4 v = *(const f32x4*)(src + i);
  #pragma unroll
  for(int q=0;q<4;q++) dst[i+q] = __float2bfloat16(v[q]);
}

// transpose + convert: src [R][C] -> dst bf16 [C][R]
__device__ inline bf16 to_b(float v){ return __float2bfloat16(v); }
__device__ inline bf16 to_b(bf16 v){ return v; }
template<typename TS>
__global__ __launch_bounds__(256)
void tr_k(const TS* __restrict__ src, bf16* __restrict__ dst, int R, int C)
{
  __shared__ bf16 tile[64][65];
  const int rb = blockIdx.y*64, cb = blockIdx.x*64, t = threadIdx.x;
  #pragma unroll
  for(int i=0;i<16;i++){
    int lin = i*256 + t;
    int tr = lin >> 6, tc = lin & 63;
    tile[tr][tc] = to_b(src[(size_t)(rb+tr)*C + cb+tc]);
  }
  __syncthreads();
  #pragma unroll
  for(int i=0;i<16;i++){
    int lin = i*256 + t;
    int tc = lin >> 6, tr = lin & 63;
    dst[(size_t)(cb+tc)*R + rb+tr] = tile[tr][tc];
  }
}

// ---------------------------------------------------------------------------
// Unified 128x128 MFMA GEMM, C = A @ Bt^T.  A,Bt bf16 row-major (A:[M,K],
// Bt:[N,K]).  ASRC: 0 = A from global, 1 = A = alpha built on the fly from
// packed adjacency + el/er/m/inv (alpha[d][s] = mu * exp(leaky(el[s]+er[d])
// - m[d]) * inv[d]).
// EPI: 0 f32 store | 1 relu->bf16 | 2 bf16 | 3 bf16 += | 4 f32 += +bias,
// leaky0.01 | 5 sign-pack 2-bit adjacency (mult2 u32 rows of 256).
// ---------------------------------------------------------------------------
template<int ASRC, int EPI>
__global__ __launch_bounds__(256)
void mfma_k(const bf16* __restrict__ Ag, const unsigned int* __restrict__ mult2,
            const float* __restrict__ el, const float* __restrict__ er,
            const float* __restrict__ cm, const float* __restrict__ cinv,
            const bf16* __restrict__ Bt, void* __restrict__ Cv,
            const float* __restrict__ bias,
            int K, int lda, int ldbt, int ldc)
{
  __shared__ unsigned int As[128*20];   // [row][20 uints]: 32 bf16 + pad (80B rows)
  __shared__ unsigned int Bs[128*20];
  const int tid = threadIdx.x;
  const int bm = blockIdx.y*128, bn = blockIdx.x*128;
  const int lane = tid & 63;
  const int wr = ((tid>>6)>>1)*64, wc = ((tid>>6)&1)*64;
  const int quad = lane >> 4, mr = lane & 15;
  const int srow = tid >> 1, seg = tid & 1;

  float erd=0.f, md=0.f, invd=0.f;
  unsigned int abase=0;
  if (ASRC==1){
    int d = bm + srow;
    erd = er[d]; md = cm[d]; invd = cinv[d];
    abase = (unsigned)d*256u;
  }
  f32x4 acc[4][4];
  #pragma unroll
  for(int i=0;i<4;i++)
    #pragma unroll
    for(int j=0;j<4;j++) acc[i][j] = (f32x4){0.f,0.f,0.f,0.f};

  for(int kb=0; kb<K; kb+=32){
    uint4 bv0 = *(const uint4*)(Bt + (size_t)(bn+srow)*ldbt + kb + seg*16);
    uint4 bv1 = *(const uint4*)(Bt + (size_t)(bn+srow)*ldbt + kb + seg*16 + 8);
    uint4 av0, av1;
    unsigned int pk[8];
    if (ASRC==0){
      av0 = *(const uint4*)(Ag + (size_t)(bm+srow)*lda + kb + seg*16);
      av1 = *(const uint4*)(Ag + (size_t)(bm+srow)*lda + kb + seg*16 + 8);
    } else {
      unsigned int mbits = mult2[abase + (kb>>4) + seg];
      const float* ep = el + kb + seg*16;
      #pragma unroll
      for(int h=0; h<4; h++){
        f32x4 ev = *(const f32x4*)(ep + h*4);
        #pragma unroll
        for(int q2=0; q2<4; q2++){
          int q = h*4+q2;
          float t = ev[q2] + erd;
          t = t > 0.f ? t : 0.2f*t;
          float mu = (float)((mbits >> (2*q)) & 3u);
          float a = mu * __expf(t - md) * invd;
          bf16 hb = __float2bfloat16(a);
          unsigned short us = *(unsigned short*)&hb;
          if (q2 & 1) pk[h*2 + (q2>>1)] |= ((unsigned int)us << 16);
          else        pk[h*2 + (q2>>1)]  = (unsigned int)us;
        }
      }
    }
    __syncthreads();
    {
      unsigned int* bd = &Bs[srow*20 + seg*8];
      *(uint4*)bd = bv0; *((uint4*)bd + 1) = bv1;
      unsigned int* ad = &As[srow*20 + seg*8];
      if (ASRC==0){ *(uint4*)ad = av0; *((uint4*)ad + 1) = av1; }
      else        { *(uint4*)ad = *(uint4*)&pk[0]; *((uint4*)ad + 1) = *(uint4*)&pk[4]; }
    }
    __syncthreads();
    short8 af[4], bfr[4];
    #pragma unroll
    for(int i=0;i<4;i++) af[i]  = *(const short8*)&As[(wr + i*16 + mr)*20 + quad*4];
    #pragma unroll
    for(int j=0;j<4;j++) bfr[j] = *(const short8*)&Bs[(wc + j*16 + mr)*20 + quad*4];
    #pragma unroll
    for(int i=0;i<4;i++)
      #pragma unroll
      for(int j=0;j<4;j++)
        acc[i][j] = __builtin_amdgcn_mfma_f32_16x16x32_bf16(af[i], bfr[j], acc[i][j], 0,0,0);
  }

  if (EPI==5){
    unsigned int* Cm = (unsigned int*)Cv;
    #pragma unroll
    for(int i=0;i<4;i++){
      #pragma unroll
      for(int j=0;j<4;j++){
        int cbase = bn + wc + j*16;
        #pragma unroll
        for(int reg=0; reg<4; reg++){
          float v = acc[i][j][reg];
          unsigned long long msk = __ballot(v > 0.f);
          if (mr == 0){
            int r = bm + wr + i*16 + quad*4 + reg;
            unsigned int x = (unsigned int)(msk >> (quad*16)) & 0xFFFFu;
            x = (x | (x << 8)) & 0x00FF00FFu;
            x = (x | (x << 4)) & 0x0F0F0F0Fu;
            x = (x | (x << 2)) & 0x33333333u;
            x = (x | (x << 1)) & 0x55555555u;
            if (r >= cbase && r < cbase + 16) x += 1u << (2*(r - cbase));
            Cm[(size_t)r*256 + (cbase>>4)] = x;
          }
        }
      }
    }
  } else {
    #pragma unroll
    for(int i=0;i<4;i++){
      #pragma unroll
      for(int j=0;j<4;j++){
        #pragma unroll
        for(int reg=0; reg<4; reg++){
          int r = bm + wr + i*16 + quad*4 + reg;
          int c = bn + wc + j*16 + mr;
          float v = acc[i][j][reg];
          if (EPI==0){ ((float*)Cv)[(size_t)r*ldc + c] = v; }
          if (EPI==1){ ((bf16*)Cv)[(size_t)r*ldc + c] = __float2bfloat16(fmaxf(v,0.f)); }
          if (EPI==2){ ((bf16*)Cv)[(size_t)r*ldc + c] = __float2bfloat16(v); }
          if (EPI==3){ bf16* p = (bf16*)Cv + (size_t)r*ldc + c;
                       *p = __float2bfloat16(v + __bfloat162float(*p)); }
          if (EPI==4){ float* p = (float*)Cv + (size_t)r*ldc + c;
                       float w = v + *p + bias[c]; *p = w > 0.f ? w : 0.01f*w; }
        }
      }
    }
  }
}

// ---------------------------------------------------------------------------
// el/er: feat bf16 [NN][1024]; el[h*NN+n] = sum feat[n,hD+d]*al[hD+d]
// ---------------------------------------------------------------------------
__global__ __launch_bounds__(256)
void elr_k(const bf16* __restrict__ feat, const float* __restrict__ al,
           const float* __restrict__ ar, float* __restrict__ el,
           float* __restrict__ er, int H)
{
  __shared__ float sd[256];
  int n = blockIdx.x, t = threadIdx.x, k0 = t*4;
  float accl = 0.f, accr = 0.f;
  #pragma unroll
  for(int q=0;q<4;q++){
    float f = __bfloat162float(feat[(size_t)n*1024 + k0 + q]);
    accl += f * al[k0+q]; accr += f * ar[k0+q];
  }
  int myh = (H==2) ? (k0 >> 9) : 0;
  for(int h=0; h<H; h++){
    float rl = br_sum(myh==h ? accl : 0.f, sd);
    float rr = br_sum(myh==h ? accr : 0.f, sd);
    if(t==0){ el[h*NN+n] = rl; er[h*NN+n] = rr; }
  }
}

// ---------------------------------------------------------------------------
// column softmax stats, one block per dst d; symmetric row-scan of mult2.
// ---------------------------------------------------------------------------
__global__ __launch_bounds__(256)
void colstats2_k(const float* __restrict__ el, const float* __restrict__ er,
                 const unsigned int* __restrict__ mult2,
                 float* __restrict__ cm, float* __restrict__ cinv)
{
  __shared__ float sd[256];
  int d = blockIdx.x, t = threadIdx.x;
  float erd = er[d];
  unsigned int bits = mult2[(size_t)d*256 + t];
  float tv[16];
  float mx = -1e30f;
  const float* ep = el + t*16;
  #pragma unroll
  for(int h=0; h<4; h++){
    f32x4 ev = *(const f32x4*)(ep + h*4);
    #pragma unroll
    for(int q2=0;q2<4;q2++){
      int q = h*4 + q2;
      unsigned int mu = (bits >> (2*q)) & 3u;
      float x = ev[q2] + erd;
      x = x > 0.f ? x : 0.2f*x;
      if (mu == 2u) x += LN2F;
      tv[q] = mu ? x : -1e30f;
      mx = fmaxf(mx, tv[q]);
    }
  }
  sd[t] = mx; __syncthreads();
  for(int s=128;s>0;s>>=1){ if(t<s) sd[t]=fmaxf(sd[t],sd[t+s]); __syncthreads(); }
  float M = sd[0]; __syncthreads();
  float sum = 0.f;
  #pragma unroll
  for(int q=0;q<16;q++) sum += (tv[q] > -1e29f) ? __expf(tv[q]-M) : 0.f;
  sum = br_sum(sum, sd);
  if(t==0){ cm[d] = M; cinv[d] = 1.f/sum; }
}

// ---------------------------------------------------------------------------
// skinny classifier (f32): out[n][c] = X[n,:]·W[:,c] + b[c], C=10
// ---------------------------------------------------------------------------
__global__ __launch_bounds__(256)
void cls_k(const float* __restrict__ X, const float* __restrict__ Wt,
           const float* __restrict__ b, float* __restrict__ out, int K)
{
  __shared__ float sd[256];
  int n = blockIdx.x, t = threadIdx.x;
  float acc[10] = {};
  for(int k=t; k<K; k+=256){
    float xv = X[(size_t)n*K + k];
    #pragma unroll
    for(int c=0;c<10;c++) acc[c] += xv * Wt[k*10 + c];
  }
  for(int c=0;c<10;c++){
    float r = br_sum(acc[c], sd);
    if(t==0) out[n*10 + c] = r + b[c];
  }
}

// ---------------------------------------------------------------------------
extern "C" void kernel_launch(void* const* d_in, const int* in_sizes, int n_in,
                              void* d_out, int out_size, void* d_ws, size_t ws_size,
                              hipStream_t stream) {
  (void)in_sizes; (void)n_in; (void)out_size; (void)ws_size;
  const float* df  = (const float*)d_in[0];
  const float* W1  = (const float*)d_in[1];
  const float* al1 = (const float*)d_in[2];
  const float* ar1 = (const float*)d_in[3];
  const float* W2  = (const float*)d_in[4];
  const float* al2 = (const float*)d_in[5];
  const float* ar2 = (const float*)d_in[6];
  const float* lw  = (const float*)d_in[7];
  const float* lb  = (const float*)d_in[8];
  const float* c1w = (const float*)d_in[9];
  const float* c1b = (const float*)d_in[10];
  const float* c2w = (const float*)d_in[11];
  const float* c2b = (const float*)d_in[12];
  float* out = (float*)d_out;

  char* Wp = (char*)d_ws;                                   // peak ~56.4 MB
  bf16* W1tb = (bf16*)(Wp);                                 // 4 MB [1024][2048], dead after feat1
  bf16* x2b  = (bf16*)(Wp);                                 // 4 MB [4096][512] (reuses W1tb)
  bf16* W2tb = (bf16*)(Wp + ( 4u<<20));                     // 2 MB [1024][1024]
  bf16* lwtb = (bf16*)(Wp + ( 6u<<20));                     // 5 MB [1024][2560]
  unsigned int* mult2 = (unsigned int*)(Wp + (11u<<20));    // 4 MB packed adj [4096][256]
  bf16* dfb  = (bf16*)(Wp + (16u<<20));                     // 16 MB [4096][2048]
  bf16* featb= (bf16*)(Wp + (32u<<20));                     // 8 MB [4096][1024]
  float* x3  = (float*)(Wp + (32u<<20));                    // 16 MB (after featb/featT dead)
  bf16* featT= (bf16*)(Wp + (40u<<20));                     // 8 MB [1024][4096]
  bf16* x1b  = (bf16*)(Wp + (48u<<20));                     // 8 MB [4096][1024]
  float* S   = (float*)(Wp + (56u<<20));                    // smalls 192 KB
  float *el1=S, *er1=S+4096, *el2=S+8192, *er2=S+16384;
  float *m1=S+24576, *i1=S+28672, *m2=S+32768, *i2=S+40960;

  // 0) prep: bf16 df + transposed bf16 weights
  cvt_k<<<8192,256,0,stream>>>(df, dfb, 8388608);
  tr_k<float><<<dim3(16,32),256,0,stream>>>(W1, W1tb, 2048, 1024);
  tr_k<float><<<dim3(16,16),256,0,stream>>>(W2, W2tb, 1024, 1024);
  tr_k<float><<<dim3(16,40),256,0,stream>>>(lw, lwtb, 2560, 1024);

  // 1) packed adjacency: sign(df @ df^T), ballot-packed 2-bit
  mfma_k<0,5><<<dim3(32,32),256,0,stream>>>(
      dfb, nullptr, nullptr,nullptr,nullptr,nullptr, dfb, mult2, nullptr,
      2048, 2048, 2048, 0);

  // 2) feat1 = df @ W1 -> bf16
  mfma_k<0,2><<<dim3(8,32),256,0,stream>>>(
      dfb, nullptr, nullptr,nullptr,nullptr,nullptr, W1tb, featb, nullptr,
      2048, 2048, 2048, 1024);

  // 3) layer-1 scores + softmax stats + feat^T
  elr_k<<<NN,256,0,stream>>>(featb, al1, ar1, el1, er1, 1);
  colstats2_k<<<NN,256,0,stream>>>(el1, er1, mult2, m1, i1);
  tr_k<bf16><<<dim3(16,64),256,0,stream>>>(featb, featT, 4096, 1024);

  // 4) x1 = relu(alpha1 @ feat1) -> bf16 (alpha built inline)
  mfma_k<1,1><<<dim3(8,32),256,0,stream>>>(
      nullptr, mult2, el1, er1, m1, i1, featT, x1b, nullptr,
      4096, 0, 4096, 1024);

  // 5) feat2 = x1 @ W2 -> bf16
  mfma_k<0,2><<<dim3(8,32),256,0,stream>>>(
      x1b, nullptr, nullptr,nullptr,nullptr,nullptr, W2tb, featb, nullptr,
      1024, 1024, 1024, 1024);

  // 6) layer-2 scores (H=2), stats per head, feat^T, per-head agg, head-sum
  elr_k<<<NN,256,0,stream>>>(featb, al2, ar2, el2, er2, 2);
  colstats2_k<<<NN,256,0,stream>>>(el2,    er2,    mult2, m2,    i2);
  colstats2_k<<<NN,256,0,stream>>>(el2+NN, er2+NN, mult2, m2+NN, i2+NN);
  tr_k<bf16><<<dim3(16,64),256,0,stream>>>(featb, featT, 4096, 1024);
  mfma_k<1,2><<<dim3(4,32),256,0,stream>>>(
      nullptr, mult2, el2, er2, m2, i2, featT, x2b, nullptr,
      4096, 0, 4096, 512);
  mfma_k<1,3><<<dim3(4,32),256,0,stream>>>(
      nullptr, mult2, el2+NN, er2+NN, m2+NN, i2+NN, featT + (size_t)512*4096,
      x2b, nullptr, 4096, 0, 4096, 512);

  // 7) x3 = leaky([df, x2] @ lin1_w + b, 0.01), split over K
  mfma_k<0,0><<<dim3(8,32),256,0,stream>>>(
      dfb, nullptr, nullptr,nullptr,nullptr,nullptr, lwtb, x3, nullptr,
      2048, 2048, 2560, 1024);
  mfma_k<0,4><<<dim3(8,32),256,0,stream>>>(
      x2b, nullptr, nullptr,nullptr,nullptr,nullptr, lwtb + 2048, x3, lb,
      512, 512, 2560, 1024);

  // 8) classifiers -> f32 out
  cls_k<<<NN,256,0,stream>>>(x3, c1w, c1b, out, 1024);
  cls_k<<<NN,256,0,stream>>>(df, c2w, c2b, out + NN*10, 2048);
}

// Round 5
// 769.526 us; speedup vs baseline: 12.3814x; 1.2566x over previous
//
#include <hip/hip_runtime.h>
#include <hip/hip_bf16.h>

typedef __hip_bfloat16 bf16;
typedef __attribute__((ext_vector_type(8))) short short8;
typedef __attribute__((ext_vector_type(4))) float f32x4;

#define NN 4096
#define LN2F 0.69314718f

__device__ inline float br_sum(float v, float* sd){
  int t = threadIdx.x;
  sd[t] = v; __syncthreads();
  for(int s=128; s>0; s>>=1){ if(t<s) sd[t]+=sd[t+s]; __syncthreads(); }
  float r = sd[0]; __syncthreads();
  return r;
}

// async global->LDS, 16B per lane; lds base wave-uniform (HW adds lane*16)
__device__ inline void gl2lds(const bf16* g, unsigned int* lds){
  __builtin_amdgcn_global_load_lds(
      (const __attribute__((address_space(1))) unsigned int*)g,
      (__attribute__((address_space(3))) unsigned int*)lds, 16, 0, 0);
}

// flat f32 -> bf16 convert (4/thread)
__global__ __launch_bounds__(256)
void cvt_k(const float* __restrict__ src, bf16* __restrict__ dst, int n)
{
  int i = (blockIdx.x*256 + threadIdx.x)*4;
  if(i >= n) return;
  f32x4 v = *(const f32x4*)(src + i);
  #pragma unroll
  for(int q=0;q<4;q++) dst[i+q] = __float2bfloat16(v[q]);
}

// merged weight prep: transpose f32 [R][C] -> bf16 [C][R] for W1/W2/lw-A,
// and duplicated transpose for lw-B (head-sum folded into K).
__global__ __launch_bounds__(256)
void prep_k(const float* __restrict__ W1, const float* __restrict__ W2,
            const float* __restrict__ lw,
            bf16* __restrict__ W1tb, bf16* __restrict__ W2tb,
            bf16* __restrict__ lwtb, bf16* __restrict__ lwtb2)
{
  int b = blockIdx.x;
  const float* src; bf16* dst; int C, rb, cb, dstld; bool dup=false;
  if (b < 512){            // W1 [2048][1024] -> [1024][2048]
    src=W1; dst=W1tb; C=1024; rb=(b>>4)<<6; cb=(b&15)<<6; dstld=2048;
  } else if (b < 768){     // W2 [1024][1024] -> [1024][1024]
    b-=512; src=W2; dst=W2tb; C=1024; rb=(b>>4)<<6; cb=(b&15)<<6; dstld=1024;
  } else if (b < 1280){    // lw rows 0..2047 -> [1024][2048]
    b-=768; src=lw; dst=lwtb; C=1024; rb=(b>>4)<<6; cb=(b&15)<<6; dstld=2048;
  } else {                 // lw rows 2048..2559 [512][1024] -> dup [1024][1024]
    b-=1280; src=lw+(size_t)2048*1024; dst=lwtb2; C=1024;
    rb=(b>>4)<<6; cb=(b&15)<<6; dstld=1024; dup=true;
  }
  __shared__ bf16 tile[64][65];
  int t = threadIdx.x;
  #pragma unroll
  for(int i=0;i<16;i++){
    int lin=i*256+t, tr=lin>>6, tc=lin&63;
    tile[tr][tc] = __float2bfloat16(src[(size_t)(rb+tr)*C + cb+tc]);
  }
  __syncthreads();
  #pragma unroll
  for(int i=0;i<16;i++){
    int lin=i*256+t, tc=lin>>6, tr=lin&63;
    bf16 v = tile[tr][tc];
    dst[(size_t)(cb+tc)*dstld + rb+tr] = v;
    if(dup) dst[(size_t)(cb+tc)*dstld + rb+tr + 512] = v;
  }
}

// bf16 transpose [R][C] -> [C][R]
__global__ __launch_bounds__(256)
void trb_k(const bf16* __restrict__ src, bf16* __restrict__ dst, int R, int C)
{
  __shared__ bf16 tile[64][65];
  const int rb = blockIdx.y*64, cb = blockIdx.x*64, t = threadIdx.x;
  #pragma unroll
  for(int i=0;i<16;i++){
    int lin=i*256+t, tr=lin>>6, tc=lin&63;
    tile[tr][tc] = src[(size_t)(rb+tr)*C + cb+tc];
  }
  __syncthreads();
  #pragma unroll
  for(int i=0;i<16;i++){
    int lin=i*256+t, tc=lin>>6, tr=lin&63;
    dst[(size_t)(cb+tc)*R + rb+tr] = tile[tr][tc];
  }
}

// ---------------------------------------------------------------------------
// MFMA GEMM, C = A @ Bt^T. Tile 128 x TN, 4 waves (2x2), m97-style
// global_load_lds staging.  ASRC: 0 = A bf16 from global (async);
// 1 = A = alpha built on the fly (padded-LDS ds_write path).
// HEADS==2: agg over 2 heads, head = bn>>9 (disjoint output columns).
// EPI: 0 f32 | 1 relu->bf16 | 2 bf16 | 4 f32 += +bias+leaky0.01 | 5 signpack.
// ---------------------------------------------------------------------------
template<int ASRC, int EPI, int TN, int HEADS>
__global__ __launch_bounds__(256)
void mfma_k(const bf16* __restrict__ Ag, const unsigned int* __restrict__ mult2,
            const float* __restrict__ el_, const float* __restrict__ er_,
            const float* __restrict__ cm_, const float* __restrict__ cinv_,
            const bf16* __restrict__ Bt_, void* __restrict__ Cv,
            const float* __restrict__ bias,
            int K, int lda, int ldbt, int ldc)
{
  constexpr int AST = (ASRC==1) ? 20 : 16;   // A row stride in u32 (pad iff ds_write)
  constexpr int NJ  = TN/32;                 // col frags per wave
  __shared__ unsigned int As[128*AST];
  __shared__ unsigned int Bs[TN*16];
  const int tid = threadIdx.x;
  const int bm = blockIdx.y*128, bn = blockIdx.x*TN;
  const int lane = tid&63, wid = tid>>6;
  const int wr = (wid>>1)*64, wc = (wid&1)*(TN/2);
  const int quad = lane>>4, mr = lane&15;
  const int L4 = lane>>2, Lc = lane&3;
  const int srow = tid>>1, seg = tid&1;

  const float* el = el_; const float* er = er_;
  const float* cm = cm_; const float* cinv = cinv_;
  const bf16* Bt = Bt_;
  int bnB = bn;
  if (HEADS==2){
    int head = bn>>9; bnB = bn & 511;
    el += head*NN; er += head*NN; cm += head*NN; cinv += head*NN;
    Bt += (size_t)head*512*4096;
  }

  float erd=0.f, md=0.f, invd=0.f; unsigned int abase=0;
  if (ASRC==1){
    int d = bm + srow;
    erd = er[d]; md = cm[d]; invd = cinv[d];
    abase = (unsigned)d*256u;
  }
  f32x4 acc[4][NJ];
  #pragma unroll
  for(int i=0;i<4;i++)
    #pragma unroll
    for(int j=0;j<NJ;j++) acc[i][j] = (f32x4){0.f,0.f,0.f,0.f};

  for(int kb=0; kb<K; kb+=32){
    unsigned int pk[8];
    if (ASRC==1){
      unsigned int mbits = mult2[abase + (kb>>4) + seg];
      const float* ep = el + kb + seg*16;
      #pragma unroll
      for(int h=0; h<4; h++){
        f32x4 ev = *(const f32x4*)(ep + h*4);
        #pragma unroll
        for(int q2=0; q2<4; q2++){
          int q = h*4+q2;
          float t = ev[q2] + erd;
          t = t > 0.f ? t : 0.2f*t;
          float mu = (float)((mbits >> (2*q)) & 3u);
          float a = mu * __expf(t - md) * invd;
          bf16 hb = __float2bfloat16(a);
          unsigned short us = *(unsigned short*)&hb;
          if (q2 & 1) pk[h*2 + (q2>>1)] |= ((unsigned int)us << 16);
          else        pk[h*2 + (q2>>1)]  = (unsigned int)us;
        }
      }
    }
    __syncthreads();   // previous iter's frag reads complete
    #pragma unroll
    for(int c2=0; c2<TN/64; c2++){
      int row = (wid*(TN/64)+c2)*16 + L4;
      gl2lds(Bt + (size_t)(bnB+row)*ldbt + kb + Lc*8, &Bs[(wid*(TN/64)+c2)*256]);
    }
    if (ASRC==0){
      #pragma unroll
      for(int c2=0; c2<2; c2++){
        int row = (wid*2+c2)*16 + L4;
        gl2lds(Ag + (size_t)(bm+row)*lda + kb + Lc*8, &As[(wid*2+c2)*256]);
      }
    } else {
      uint4* ad = (uint4*)&As[srow*20 + seg*8];
      ad[0] = *(uint4*)&pk[0]; ad[1] = *(uint4*)&pk[4];
    }
    __syncthreads();   // drains vmcnt (async LDS-DMA) + lgkm
    short8 af[4], bfr[NJ];
    #pragma unroll
    for(int i=0;i<4;i++)  af[i]  = *(const short8*)&As[(wr + i*16 + mr)*AST + quad*4];
    #pragma unroll
    for(int j=0;j<NJ;j++) bfr[j] = *(const short8*)&Bs[(wc + j*16 + mr)*16 + quad*4];
    #pragma unroll
    for(int i=0;i<4;i++)
      #pragma unroll
      for(int j=0;j<NJ;j++)
        acc[i][j] = __builtin_amdgcn_mfma_f32_16x16x32_bf16(af[i], bfr[j], acc[i][j], 0,0,0);
  }

  if (EPI==5){
    unsigned int* Cm = (unsigned int*)Cv;
    #pragma unroll
    for(int i=0;i<4;i++){
      #pragma unroll
      for(int j=0;j<NJ;j++){
        int cbase = bn + wc + j*16;
        #pragma unroll
        for(int reg=0; reg<4; reg++){
          float v = acc[i][j][reg];
          unsigned long long msk = __ballot(v > 0.f);
          if (mr == 0){
            int r = bm + wr + i*16 + quad*4 + reg;
            unsigned int x = (unsigned int)(msk >> (quad*16)) & 0xFFFFu;
            x = (x | (x << 8)) & 0x00FF00FFu;
            x = (x | (x << 4)) & 0x0F0F0F0Fu;
            x = (x | (x << 2)) & 0x33333333u;
            x = (x | (x << 1)) & 0x55555555u;
            if (r >= cbase && r < cbase + 16) x += 1u << (2*(r - cbase));
            Cm[(size_t)r*256 + (cbase>>4)] = x;
          }
        }
      }
    }
  } else {
    #pragma unroll
    for(int i=0;i<4;i++){
      #pragma unroll
      for(int j=0;j<NJ;j++){
        #pragma unroll
        for(int reg=0; reg<4; reg++){
          int r = bm + wr + i*16 + quad*4 + reg;
          int c = bn + wc + j*16 + mr;
          float v = acc[i][j][reg];
          if (EPI==0){ ((float*)Cv)[(size_t)r*ldc + c] = v; }
          if (EPI==1){ ((bf16*)Cv)[(size_t)r*ldc + c] = __float2bfloat16(fmaxf(v,0.f)); }
          if (EPI==2){ ((bf16*)Cv)[(size_t)r*ldc + c] = __float2bfloat16(v); }
          if (EPI==4){ float* p = (float*)Cv + (size_t)r*ldc + c;
                       float w = v + *p + bias[c]; *p = w > 0.f ? w : 0.01f*w; }
        }
      }
    }
  }
}

// ---------------------------------------------------------------------------
// el/er: feat bf16 [NN][1024]; el[h*NN+n] = sum feat[n,hD+d]*al[hD+d]
// ---------------------------------------------------------------------------
__global__ __launch_bounds__(256)
void elr_k(const bf16* __restrict__ feat, const float* __restrict__ al,
           const float* __restrict__ ar, float* __restrict__ el,
           float* __restrict__ er, int H)
{
  __shared__ float sd[256];
  int n = blockIdx.x, t = threadIdx.x, k0 = t*4;
  float accl = 0.f, accr = 0.f;
  #pragma unroll
  for(int q=0;q<4;q++){
    float f = __bfloat162float(feat[(size_t)n*1024 + k0 + q]);
    accl += f * al[k0+q]; accr += f * ar[k0+q];
  }
  int myh = (H==2) ? (k0 >> 9) : 0;
  for(int h=0; h<H; h++){
    float rl = br_sum(myh==h ? accl : 0.f, sd);
    float rr = br_sum(myh==h ? accr : 0.f, sd);
    if(t==0){ el[h*NN+n] = rl; er[h*NN+n] = rr; }
  }
}

// ---------------------------------------------------------------------------
// column softmax stats, one block per dst d; symmetric row-scan of mult2.
// ---------------------------------------------------------------------------
__global__ __launch_bounds__(256)
void colstats2_k(const float* __restrict__ el, const float* __restrict__ er,
                 const unsigned int* __restrict__ mult2,
                 float* __restrict__ cm, float* __restrict__ cinv)
{
  __shared__ float sd[256];
  int d = blockIdx.x, t = threadIdx.x;
  float erd = er[d];
  unsigned int bits = mult2[(size_t)d*256 + t];
  float tv[16];
  float mx = -1e30f;
  const float* ep = el + t*16;
  #pragma unroll
  for(int h=0; h<4; h++){
    f32x4 ev = *(const f32x4*)(ep + h*4);
    #pragma unroll
    for(int q2=0;q2<4;q2++){
      int q = h*4 + q2;
      unsigned int mu = (bits >> (2*q)) & 3u;
      float x = ev[q2] + erd;
      x = x > 0.f ? x : 0.2f*x;
      if (mu == 2u) x += LN2F;
      tv[q] = mu ? x : -1e30f;
      mx = fmaxf(mx, tv[q]);
    }
  }
  sd[t] = mx; __syncthreads();
  for(int s=128;s>0;s>>=1){ if(t<s) sd[t]=fmaxf(sd[t],sd[t+s]); __syncthreads(); }
  float M = sd[0]; __syncthreads();
  float sum = 0.f;
  #pragma unroll
  for(int q=0;q<16;q++) sum += (tv[q] > -1e29f) ? __expf(tv[q]-M) : 0.f;
  sum = br_sum(sum, sd);
  if(t==0){ cm[d] = M; cinv[d] = 1.f/sum; }
}

// ---------------------------------------------------------------------------
// merged classifiers: blocks 0..4095 -> logits1 (x3,K=1024), 4096.. -> logits2
// ---------------------------------------------------------------------------
__global__ __launch_bounds__(256)
void cls2_k(const float* __restrict__ x3, const float* __restrict__ df,
            const float* __restrict__ c1w, const float* __restrict__ c1b,
            const float* __restrict__ c2w, const float* __restrict__ c2b,
            float* __restrict__ out)
{
  __shared__ float sd[256];
  int b = blockIdx.x, t = threadIdx.x;
  const float* X; const float* Wt; const float* bi; int K, n; float* o;
  if (b < 4096){ X = x3; Wt = c1w; bi = c1b; K = 1024; n = b;      o = out; }
  else         { X = df; Wt = c2w; bi = c2b; K = 2048; n = b-4096; o = out + NN*10; }
  float acc[10] = {};
  for(int k=t; k<K; k+=256){
    float xv = X[(size_t)n*K + k];
    #pragma unroll
    for(int c=0;c<10;c++) acc[c] += xv * Wt[k*10 + c];
  }
  for(int c=0;c<10;c++){
    float r = br_sum(acc[c], sd);
    if(t==0) o[n*10 + c] = r + bi[c];
  }
}

// ---------------------------------------------------------------------------
extern "C" void kernel_launch(void* const* d_in, const int* in_sizes, int n_in,
                              void* d_out, int out_size, void* d_ws, size_t ws_size,
                              hipStream_t stream) {
  (void)in_sizes; (void)n_in; (void)out_size; (void)ws_size;
  const float* df  = (const float*)d_in[0];
  const float* W1  = (const float*)d_in[1];
  const float* al1 = (const float*)d_in[2];
  const float* ar1 = (const float*)d_in[3];
  const float* W2  = (const float*)d_in[4];
  const float* al2 = (const float*)d_in[5];
  const float* ar2 = (const float*)d_in[6];
  const float* lw  = (const float*)d_in[7];
  const float* lb  = (const float*)d_in[8];
  const float* c1w = (const float*)d_in[9];
  const float* c1b = (const float*)d_in[10];
  const float* c2w = (const float*)d_in[11];
  const float* c2b = (const float*)d_in[12];
  float* out = (float*)d_out;

  char* Wp = (char*)d_ws;                                   // peak ~56.2 MB
  bf16* W1tb  = (bf16*)(Wp);                                // 4 MB [1024][2048]
  bf16* W2tb  = (bf16*)(Wp + ( 4u<<20));                    // 2 MB [1024][1024]
  bf16* lwtb  = (bf16*)(Wp + ( 6u<<20));                    // 4 MB [1024][2048]
  bf16* lwtb2 = (bf16*)(Wp + (10u<<20));                    // 2 MB [1024][1024] dup
  unsigned int* mult2 = (unsigned int*)(Wp + (12u<<20));    // 4 MB packed adj
  bf16* dfb   = (bf16*)(Wp + (16u<<20));                    // 16 MB [4096][2048]
  bf16* featb = (bf16*)(Wp + (32u<<20));                    // 8 MB [4096][1024]
  float* x3   = (float*)(Wp + (32u<<20));                   // 16 MB (featb/featT dead)
  bf16* featT = (bf16*)(Wp + (40u<<20));                    // 8 MB [1024][4096]
  bf16* x1b   = (bf16*)(Wp + (48u<<20));                    // 8 MB [4096][1024]
  bf16* x2cat = (bf16*)(Wp + (48u<<20));                    // 8 MB (x1b dead)
  float* S    = (float*)(Wp + (56u<<20));                   // smalls 192 KB
  float *el1=S, *er1=S+4096, *el2=S+8192, *er2=S+16384;
  float *m1=S+24576, *i1=S+28672, *m2=S+32768, *i2=S+40960;

  // 0) prep: bf16 df + transposed bf16 weights (merged)
  cvt_k<<<8192,256,0,stream>>>(df, dfb, 8388608);
  prep_k<<<1408,256,0,stream>>>(W1, W2, lw, W1tb, W2tb, lwtb, lwtb2);

  // 1) packed adjacency: sign(df @ df^T), ballot-packed 2-bit (1024 blocks)
  mfma_k<0,5,128,1><<<dim3(32,32),256,0,stream>>>(
      dfb, nullptr, nullptr,nullptr,nullptr,nullptr, dfb, mult2, nullptr,
      2048, 2048, 2048, 0);

  // 2) feat1 = df @ W1 -> bf16 (512 blocks)
  mfma_k<0,2,64,1><<<dim3(16,32),256,0,stream>>>(
      dfb, nullptr, nullptr,nullptr,nullptr,nullptr, W1tb, featb, nullptr,
      2048, 2048, 2048, 1024);

  // 3) layer-1 scores + softmax stats + feat^T
  elr_k<<<NN,256,0,stream>>>(featb, al1, ar1, el1, er1, 1);
  colstats2_k<<<NN,256,0,stream>>>(el1, er1, mult2, m1, i1);
  trb_k<<<dim3(16,64),256,0,stream>>>(featb, featT, 4096, 1024);

  // 4) x1 = relu(alpha1 @ feat1) -> bf16 (512 blocks, alpha inline)
  mfma_k<1,1,64,1><<<dim3(16,32),256,0,stream>>>(
      nullptr, mult2, el1, er1, m1, i1, featT, x1b, nullptr,
      4096, 0, 4096, 1024);

  // 5) feat2 = x1 @ W2 -> bf16 (512 blocks)
  mfma_k<0,2,64,1><<<dim3(16,32),256,0,stream>>>(
      x1b, nullptr, nullptr,nullptr,nullptr,nullptr, W2tb, featb, nullptr,
      1024, 1024, 1024, 1024);

  // 6) layer-2 scores (H=2), stats per head, feat^T, fused 2-head agg
  elr_k<<<NN,256,0,stream>>>(featb, al2, ar2, el2, er2, 2);
  colstats2_k<<<NN,256,0,stream>>>(el2,    er2,    mult2, m2,    i2);
  colstats2_k<<<NN,256,0,stream>>>(el2+NN, er2+NN, mult2, m2+NN, i2+NN);
  trb_k<<<dim3(16,64),256,0,stream>>>(featb, featT, 4096, 1024);
  mfma_k<1,2,64,2><<<dim3(16,32),256,0,stream>>>(
      nullptr, mult2, el2, er2, m2, i2, featT, x2cat, nullptr,
      4096, 0, 4096, 1024);

  // 7) x3 = leaky([df, x2h0+x2h1] @ lin1_w + b, 0.01); head-sum folded into
  //    K=1024 GEMM with duplicated weight rows (linearity)
  mfma_k<0,0,64,1><<<dim3(16,32),256,0,stream>>>(
      dfb, nullptr, nullptr,nullptr,nullptr,nullptr, lwtb, x3, nullptr,
      2048, 2048, 2048, 1024);
  mfma_k<0,4,64,1><<<dim3(16,32),256,0,stream>>>(
      x2cat, nullptr, nullptr,nullptr,nullptr,nullptr, lwtb2, x3, lb,
      1024, 1024, 1024, 1024);

  // 8) merged classifiers -> f32 out
  cls2_k<<<8192,256,0,stream>>>(x3, df, c1w, c1b, c2w, c2b, out);
}